// Round 14
// baseline (261.608 us; speedup 1.0000x reference)
//
#include <hip/hip_runtime.h>
#include <hip/hip_fp16.h>

typedef float f32x4 __attribute__((ext_vector_type(4)));
typedef float f32x2 __attribute__((ext_vector_type(2)));
typedef _Float16 f16x8 __attribute__((ext_vector_type(8)));
typedef __fp16 fp16x2 __attribute__((ext_vector_type(2)));   // cvt_pkrtz return type

#define T_LEN 96
#define DM    256
#define NSAMP 32      // ODE rows per block
#define MT 2          // d-tiles per wave (wave owns 32 d)
#define NT 2          // sample-tiles per wave
#define BUF_USH 8192  // 32 rows * 256 f16 per stage buffer (16KB)
// LDS map (bytes): buf0 [0,16K), buf1 [16K,32K), yf [32K,64K) — all disjoint.
// Total 64KB -> 2 blocks/CU -> backend targets 4 waves/EU -> 128-VGPR budget.

// fast softplus: ~7 instr; |err| ~1e-7, threshold 3.9e-2
__device__ __forceinline__ float softplus_f(float x){
    float u = __expf(-fabsf(x));
    return fmaxf(x, 0.f) + __logf(1.0f + u);
}
__device__ __forceinline__ uint pkrtz(float a, float b){
    fp16x2 h = __builtin_amdgcn_cvt_pkrtz(a, b);
    return *(uint*)&h;
}
// packed dual-f32 math (VOP3P, CDNA2+): 2 elements / instruction
__device__ __forceinline__ f32x2 pk_add(f32x2 a, f32x2 b){
    f32x2 d; asm("v_pk_add_f32 %0, %1, %2" : "=v"(d) : "v"(a), "v"(b)); return d;
}
__device__ __forceinline__ f32x2 pk_mul(f32x2 a, f32x2 b){
    f32x2 d; asm("v_pk_mul_f32 %0, %1, %2" : "=v"(d) : "v"(a), "v"(b)); return d;
}
__device__ __forceinline__ f32x2 pk_fma(f32x2 a, f32x2 b, f32x2 c){
    f32x2 d; asm("v_pk_fma_f32 %0, %1, %2, %3" : "=v"(d) : "v"(a), "v"(b), "v"(c)); return d;
}
__device__ __forceinline__ f32x2 lo2(f32x4 v){ return __builtin_shufflevector(v, v, 0, 1); }
__device__ __forceinline__ f32x2 hi2(f32x4 v){ return __builtin_shufflevector(v, v, 2, 3); }
__device__ __forceinline__ f32x2 bc2(float s){ return (f32x2){s, s}; }

// Convert W to f16 and pack into MFMA A-fragment order:
// frag (dt,ks): lane l holds W[dt*16 + (l&15)][ks*32 + (l>>4)*8 + i], i=0..7
__global__ void pack_w_kernel(const float* __restrict__ W1, const float* __restrict__ W2,
                              ushort* __restrict__ ws){
    int idx = blockIdx.x*256 + threadIdx.x;          // 0..65535
    const float* W = blockIdx.y ? W2 : W1;
    ushort* dst = ws + (size_t)blockIdx.y*65536;     // [W1f16 | W2f16]
    float w = W[idx];
    int d = idx >> 8, k = idx & 255;
    int off = ((((d>>4)<<3) + (k>>5))<<9) + (((d&15) | (((k>>3)&3)<<4))<<3) + (k&7);
    dst[off] = __half_as_ushort(__float2half_rn(w));
}

__global__ __launch_bounds__(512)
void ode_mfma_kernel(const float* __restrict__ x, const float* __restrict__ t,
                     const float* __restrict__ b1, const float* __restrict__ u1,
                     const float* __restrict__ b2, const float* __restrict__ u2,
                     const ushort* __restrict__ wpk, float* __restrict__ out)
{
    __shared__ __align__(16) ushort ylds[4*BUF_USH];   // 64KB

    const int tid  = threadIdx.x;
    const int wvd  = tid >> 6;       // wave 0..7 owns d in [32*wvd, 32*wvd+32)
    const int lane = tid & 63;
    const int l15  = lane & 15;
    const int l4   = lane >> 4;
    const int base = blockIdx.x * NSAMP;

    float t0v[NT], rat[NT];
    f32x2 rat2[NT];
    f32x2 y[MT][NT][2], k1[MT][NT][2], k2[MT][NT][2];
    f32x4 acc[MT][NT];

    // hoisted layer-2 bias/u (16 VGPRs) — used in 4 extract phases + k4 per step
    f32x2 B2h[MT][2], U2h[MT][2];
#pragma unroll
    for(int mt=0; mt<MT; mt++){
        const int db = 32*wvd + mt*16 + l4*4;
        f32x4 bv = *(const f32x4*)(b2 + db);
        f32x4 uv = *(const f32x4*)(u2 + db);
        B2h[mt][0]=lo2(bv); B2h[mt][1]=hi2(bv);
        U2h[mt][0]=lo2(uv); U2h[mt][1]=hi2(uv);
    }

    // hoisted put byte-indices (ushort index into buf0; buf1 = +BUF_USH)
    int pofs[MT][NT];
#pragma unroll
    for(int mt=0; mt<MT; mt++)
#pragma unroll
        for(int nt=0; nt<NT; nt++){
            int row = nt*16 + l15;
            int gs  = (4*wvd + 2*mt + (l4>>1)) ^ (row & 7);
            pofs[mt][nt] = row*256 + gs*8 + (l4&1)*4;
        }

    // hoisted B-read swizzled base byte-offsets: read addr = vb[nt] ^ (64*ks)
    int vb[NT];
#pragma unroll
    for(int nt=0; nt<NT; nt++){
        int row = nt*16 + l15;
        vb[nt] = row*512 + ((l4 ^ (row&3))*16) + ((row&4)*16);
    }

#pragma unroll
    for(int nt=0; nt<NT; nt++){
        int n = base + nt*16 + l15;
        int b = n / (T_LEN*T_LEN);
        int r = n - b*(T_LEN*T_LEN);
        int q = r / T_LEN;
        int j = r - q*T_LEN;
        float ta = t[b*T_LEN + j], tb = t[b*T_LEN + q];
        t0v[nt] = ta; rat[nt] = tb - ta; rat2[nt] = bc2(tb - ta);
        const float* xr = x + (size_t)(b*T_LEN + j)*DM;
#pragma unroll
        for(int mt=0; mt<MT; mt++){
            const int db = 32*wvd + mt*16 + l4*4;
            f32x4 v = *(const f32x4*)(xr + db);
            y[mt][nt][0] = lo2(v); y[mt][nt][1] = hi2(v);
        }
    }

    // write 4 consecutive-d values as f16 (8B) at hoisted index
    auto put = [&](int idx, f32x2 v01, f32x2 v23){
        uint p0 = pkrtz(v01[0], v01[1]), p1 = pkrtz(v23[0], v23[1]);
        *(uint2*)&ylds[idx] = make_uint2(p0, p1);
    };

    // acc[mt][nt] = (W-slice) x Y^T over K=256, single f16 product
    auto matmul = [&](const ushort* Wf, int buf){
        const char* bb = (const char*)ylds + (buf<<14);
        __builtin_amdgcn_s_setprio(1);
#pragma unroll
        for(int mt=0; mt<MT; mt++)
#pragma unroll
            for(int nt=0; nt<NT; nt++)
                acc[mt][nt] = (f32x4){0.f,0.f,0.f,0.f};
#pragma unroll 2
        for(int ks=0; ks<8; ks++){
            f16x8 ah[MT];
#pragma unroll
            for(int mt=0; mt<MT; mt++){
                const int off = ((((2*wvd+mt)<<3)+ks)<<9) + (lane<<3);
                ah[mt] = *(const f16x8*)(Wf + off);
            }
#pragma unroll
            for(int nt=0; nt<NT; nt++){
                f16x8 bh = *(const f16x8*)(bb + (vb[nt] ^ (ks<<6)));
#pragma unroll
                for(int mt=0; mt<MT; mt++)
                    acc[mt][nt] = __builtin_amdgcn_mfma_f32_16x16x32_f16(ah[mt], bh, acc[mt][nt], 0,0,0);
            }
        }
        __builtin_amdgcn_s_setprio(0);
    };

    // softplus + stage hidden into buf1 (after matmul1's acc)
    auto hidden = [&](const f32x2* tt2){
#pragma unroll
        for(int mt=0; mt<MT; mt++){
            const int db = 32*wvd + mt*16 + l4*4;
            f32x4 bv = *(const f32x4*)(b1 + db);
            f32x4 uv = *(const f32x4*)(u1 + db);
            f32x2 bp[2] = {lo2(bv), hi2(bv)}, up[2] = {lo2(uv), hi2(uv)};
#pragma unroll
            for(int nt=0; nt<NT; nt++){
                f32x2 v[2];
#pragma unroll
                for(int p=0;p<2;p++){
                    f32x2 ap = p ? hi2(acc[mt][nt]) : lo2(acc[mt][nt]);
                    f32x2 s  = pk_fma(tt2[nt], up[p], pk_add(ap, bp[p]));
                    v[p] = (f32x2){ softplus_f(s[0]), softplus_f(s[1]) };
                }
                put(BUF_USH + pofs[mt][nt], v[0], v[1]);
            }
        }
    };

    // ---- initial stage of y into buf0
#pragma unroll
    for(int mt=0; mt<MT; mt++)
#pragma unroll
        for(int nt=0; nt<NT; nt++)
            put(pofs[mt][nt], y[mt][nt][0], y[mt][nt][1]);
    __syncthreads();

    const f32x2 neg1 = bc2(-1.f), four2 = bc2(4.f), three2 = bc2(3.f);

    float s0 = 0.f;
#pragma unroll 1
    for(int step=0; step<3; step++){
        const float s1 = (step==0) ? 0.1127016653792583f : ((step==1) ? 0.5f : 0.8872983346207417f);
        const float gw = ((step==1) ? 0.88888f : 0.55555f) * 0.5f;
        const float dt = s1 - s0;
        const float c3 = dt * (1.f/3.f);
        const f32x2 dt2 = bc2(dt), c32 = bc2(c3), nc32 = bc2(-c3), dt82 = bc2(dt*0.125f);
        const f32x2 gw2 = bc2(gw);
        f32x2 tt2[NT];

        // ---- E1
#pragma unroll
        for(int nt=0; nt<NT; nt++) tt2[nt] = bc2(t0v[nt] + s0*rat[nt]);
        matmul(wpk, 0);
        hidden(tt2);
        __syncthreads();
        matmul(wpk + 65536, 1);

        // ---- k1 extract; stage y + c3*k1 -> buf0
#pragma unroll
        for(int mt=0; mt<MT; mt++)
#pragma unroll
            for(int nt=0; nt<NT; nt++){
                f32x2 v[2];
#pragma unroll
                for(int p=0;p<2;p++){
                    f32x2 ap = p ? hi2(acc[mt][nt]) : lo2(acc[mt][nt]);
                    f32x2 kk = pk_mul(pk_fma(tt2[nt], U2h[mt][p], pk_add(ap, B2h[mt][p])), rat2[nt]);
                    k1[mt][nt][p] = kk;
                    v[p] = pk_fma(c32, kk, y[mt][nt][p]);
                }
                put(pofs[mt][nt], v[0], v[1]);
            }
        __syncthreads();

        // ---- E2
#pragma unroll
        for(int nt=0; nt<NT; nt++) tt2[nt] = bc2(t0v[nt] + (s0+c3)*rat[nt]);
        matmul(wpk, 0);
        hidden(tt2);
        __syncthreads();
        matmul(wpk + 65536, 1);

        // ---- k2 extract; stage y + dt*k2 - c3*k1 -> buf0; k1 <- d12 = k1-k2
#pragma unroll
        for(int mt=0; mt<MT; mt++)
#pragma unroll
            for(int nt=0; nt<NT; nt++){
                f32x2 v[2];
#pragma unroll
                for(int p=0;p<2;p++){
                    f32x2 ap = p ? hi2(acc[mt][nt]) : lo2(acc[mt][nt]);
                    f32x2 kk = pk_mul(pk_fma(tt2[nt], U2h[mt][p], pk_add(ap, B2h[mt][p])), rat2[nt]);
                    f32x2 k1o = k1[mt][nt][p];
                    v[p] = pk_fma(dt2, kk, pk_fma(nc32, k1o, y[mt][nt][p]));
                    k1[mt][nt][p] = pk_fma(kk, neg1, k1o);   // d12 = k1 - k2
                    k2[mt][nt][p] = kk;
                }
                put(pofs[mt][nt], v[0], v[1]);
            }
        __syncthreads();

        // ---- E3
#pragma unroll
        for(int nt=0; nt<NT; nt++) tt2[nt] = bc2(t0v[nt] + (s0+2.f*c3)*rat[nt]);
        matmul(wpk, 0);
        hidden(tt2);
        __syncthreads();
        matmul(wpk + 65536, 1);

        // ---- k3 extract: stage y + dt*(d12+k3) -> buf0;
        //      y += dt8*(d12 + 4*k2 + 3*k3)   [= dt8*(k1+3(k2+k3))]
#pragma unroll
        for(int mt=0; mt<MT; mt++)
#pragma unroll
            for(int nt=0; nt<NT; nt++){
                f32x2 v[2];
#pragma unroll
                for(int p=0;p<2;p++){
                    f32x2 ap = p ? hi2(acc[mt][nt]) : lo2(acc[mt][nt]);
                    f32x2 k3v = pk_mul(pk_fma(tt2[nt], U2h[mt][p], pk_add(ap, B2h[mt][p])), rat2[nt]);
                    f32x2 d12 = k1[mt][nt][p];
                    v[p] = pk_fma(dt2, pk_add(d12, k3v), y[mt][nt][p]);
                    f32x2 inner = pk_fma(four2, k2[mt][nt][p], pk_fma(three2, k3v, d12));
                    y[mt][nt][p] = pk_fma(dt82, inner, y[mt][nt][p]);
                }
                put(pofs[mt][nt], v[0], v[1]);
            }
        __syncthreads();

        // ---- E4
#pragma unroll
        for(int nt=0; nt<NT; nt++) tt2[nt] = bc2(t0v[nt] + s1*rat[nt]);
        matmul(wpk, 0);
        hidden(tt2);
        __syncthreads();
        matmul(wpk + 65536, 1);

        // ---- k4 fold + stage next y (buf0) + transpose scratch (yf, disjoint)
        {
            float* yf = (float*)&ylds[2*BUF_USH];   // [32 rows][256 f32], swizzled
#pragma unroll
            for(int mt=0; mt<MT; mt++)
#pragma unroll
                for(int nt=0; nt<NT; nt++){
                    const int row = nt*16 + l15;
                    f32x4 ov;
#pragma unroll
                    for(int p=0;p<2;p++){
                        f32x2 ap = p ? hi2(acc[mt][nt]) : lo2(acc[mt][nt]);
                        f32x2 k4v = pk_mul(pk_fma(tt2[nt], U2h[mt][p], pk_add(ap, B2h[mt][p])), rat2[nt]);
                        f32x2 yn  = pk_fma(dt82, k4v, y[mt][nt][p]);
                        y[mt][nt][p] = yn;
                        f32x2 o = pk_mul(yn, gw2);
                        ov[2*p] = o[0]; ov[2*p+1] = o[1];
                    }
                    put(pofs[mt][nt], y[mt][nt][0], y[mt][nt][1]);
                    const int c = 8*wvd + 4*mt + l4;
                    const int p2 = c ^ (row & 7);
                    *(f32x4*)&yf[row*256 + p2*4] = ov;
                }
            __syncthreads();
#pragma unroll
            for(int i=0;i<4;i++){
                const int r = 4*wvd + i;
                f32x4 v = *(const f32x4*)&yf[r*256 + ((lane ^ (r&7))&63)*4];
                __builtin_nontemporal_store(v,
                    (f32x4*)(out + ((size_t)(base + r)*3 + step)*DM + lane*4));
            }
        }
        s0 = s1;
    }
}

extern "C" void kernel_launch(void* const* d_in, const int* in_sizes, int n_in,
                              void* d_out, int out_size, void* d_ws, size_t ws_size,
                              hipStream_t stream)
{
    const float* x  = (const float*)d_in[0];
    const float* t  = (const float*)d_in[1];
    const float* W1 = (const float*)d_in[2];
    const float* b1 = (const float*)d_in[3];
    const float* u1 = (const float*)d_in[4];
    const float* W2 = (const float*)d_in[5];
    const float* b2 = (const float*)d_in[6];
    const float* u2 = (const float*)d_in[7];
    ushort* wpk = (ushort*)d_ws;     // 256 KB: W1f16 | W2f16 packed fragments

    pack_w_kernel<<<dim3(256,2), 256, 0, stream>>>(W1, W2, wpk);
    ode_mfma_kernel<<<dim3((4*T_LEN*T_LEN)/NSAMP), 512, 0, stream>>>(
        x, t, b1, u1, b2, u2, wpk, (float*)d_out);
}

// Round 15
// 196.212 us; speedup vs baseline: 1.3333x; 1.3333x over previous
//
#include <hip/hip_runtime.h>
#include <hip/hip_fp16.h>

typedef float f32x4 __attribute__((ext_vector_type(4)));
typedef float f32x2 __attribute__((ext_vector_type(2)));
typedef _Float16 f16x8 __attribute__((ext_vector_type(8)));
typedef __fp16 fp16x2 __attribute__((ext_vector_type(2)));   // cvt_pkrtz return type

#define T_LEN 96
#define DM    256
#define NSAMP 32      // ODE rows per block
#define MT 2          // d-tiles per wave (wave owns 32 d)
#define NT 2          // sample-tiles per wave
#define BUF_USH 8192  // 32 rows * 256 f16 per stage buffer (16KB)
// LDS map (ushort idx): buf0 [0,8192), buf1 [8192,16384), yf [16384,32768),
// pad to 49152 (96KB total). 96KB > 80KB -> exactly 1 block/CU -> 8 waves =
// 2 waves/EU -> VGPR budget 256 (R4-R9 allocator law, now used in reverse):
// room to keep ALL W fragments (128 VGPRs) register-resident, killing the
// per-eval 16KB/wave W re-stream from L2 (~246 kcyc, the R14-diagnosed
// critical-path term).
#define LDS_TOTAL 49152

__device__ __forceinline__ float softplus_f(float x){
    float u = __expf(-fabsf(x));
    return fmaxf(x, 0.f) + __logf(1.0f + u);
}
__device__ __forceinline__ uint pkrtz(float a, float b){
    fp16x2 h = __builtin_amdgcn_cvt_pkrtz(a, b);
    return *(uint*)&h;
}
__device__ __forceinline__ f32x2 pk_add(f32x2 a, f32x2 b){
    f32x2 d; asm("v_pk_add_f32 %0, %1, %2" : "=v"(d) : "v"(a), "v"(b)); return d;
}
__device__ __forceinline__ f32x2 pk_mul(f32x2 a, f32x2 b){
    f32x2 d; asm("v_pk_mul_f32 %0, %1, %2" : "=v"(d) : "v"(a), "v"(b)); return d;
}
__device__ __forceinline__ f32x2 pk_fma(f32x2 a, f32x2 b, f32x2 c){
    f32x2 d; asm("v_pk_fma_f32 %0, %1, %2, %3" : "=v"(d) : "v"(a), "v"(b), "v"(c)); return d;
}
__device__ __forceinline__ f32x2 lo2(f32x4 v){ return __builtin_shufflevector(v, v, 0, 1); }
__device__ __forceinline__ f32x2 hi2(f32x4 v){ return __builtin_shufflevector(v, v, 2, 3); }
__device__ __forceinline__ f32x2 bc2(float s){ return (f32x2){s, s}; }

// Convert W to f16 and pack into MFMA A-fragment order:
// frag (dt,ks): lane l holds W[dt*16 + (l&15)][ks*32 + (l>>4)*8 + i], i=0..7
__global__ void pack_w_kernel(const float* __restrict__ W1, const float* __restrict__ W2,
                              ushort* __restrict__ ws){
    int idx = blockIdx.x*256 + threadIdx.x;          // 0..65535
    const float* W = blockIdx.y ? W2 : W1;
    ushort* dst = ws + (size_t)blockIdx.y*65536;     // [W1f16 | W2f16]
    float w = W[idx];
    int d = idx >> 8, k = idx & 255;
    int off = ((((d>>4)<<3) + (k>>5))<<9) + (((d&15) | (((k>>3)&3)<<4))<<3) + (k&7);
    dst[off] = __half_as_ushort(__float2half_rn(w));
}

__global__ __launch_bounds__(512)
void ode_mfma_kernel(const float* __restrict__ x, const float* __restrict__ t,
                     const float* __restrict__ b1, const float* __restrict__ u1,
                     const float* __restrict__ b2, const float* __restrict__ u2,
                     const ushort* __restrict__ wpk, float* __restrict__ out)
{
    __shared__ __align__(16) ushort ylds[LDS_TOTAL];   // 96KB, map above

    const int tid  = threadIdx.x;
    const int wvd  = tid >> 6;       // wave 0..7 owns d in [32*wvd, 32*wvd+32)
    const int lane = tid & 63;
    const int l15  = lane & 15;
    const int l4   = lane >> 4;
    const int base = blockIdx.x * NSAMP;

    // ---- register-resident W fragments: 32 x f16x8 = 128 VGPRs, loaded ONCE.
    //      All indexing compile-time (full unroll) so they stay in registers.
    f16x8 W1f[MT][8], W2f[MT][8];
#pragma unroll
    for(int mt=0; mt<MT; mt++)
#pragma unroll
        for(int ks=0; ks<8; ks++){
            const int off = ((((2*wvd+mt)<<3)+ks)<<9) + (lane<<3);
            W1f[mt][ks] = *(const f16x8*)(wpk + off);
            W2f[mt][ks] = *(const f16x8*)(wpk + 65536 + off);
        }

    float t0v[NT], rat[NT];
    f32x2 rat2[NT];
    f32x2 y[MT][NT][2], k1[MT][NT][2], k2[MT][NT][2];
    f32x4 acc[MT][NT];

    // hoisted per-layer bias/u (32 VGPRs total)
    f32x2 B1h[MT][2], U1h[MT][2], B2h[MT][2], U2h[MT][2];
#pragma unroll
    for(int mt=0; mt<MT; mt++){
        const int db = 32*wvd + mt*16 + l4*4;
        f32x4 b1v = *(const f32x4*)(b1 + db);
        f32x4 u1v = *(const f32x4*)(u1 + db);
        f32x4 b2v = *(const f32x4*)(b2 + db);
        f32x4 u2v = *(const f32x4*)(u2 + db);
        B1h[mt][0]=lo2(b1v); B1h[mt][1]=hi2(b1v);
        U1h[mt][0]=lo2(u1v); U1h[mt][1]=hi2(u1v);
        B2h[mt][0]=lo2(b2v); B2h[mt][1]=hi2(b2v);
        U2h[mt][0]=lo2(u2v); U2h[mt][1]=hi2(u2v);
    }

    // hoisted put byte-indices (ushort index into buf0; buf1 = +BUF_USH)
    int pofs[MT][NT];
#pragma unroll
    for(int mt=0; mt<MT; mt++)
#pragma unroll
        for(int nt=0; nt<NT; nt++){
            int row = nt*16 + l15;
            int gs  = (4*wvd + 2*mt + (l4>>1)) ^ (row & 7);
            pofs[mt][nt] = row*256 + gs*8 + (l4&1)*4;
        }

    // hoisted B-read swizzled base byte-offsets: read addr = vb[nt] ^ (64*ks)
    int vb[NT];
#pragma unroll
    for(int nt=0; nt<NT; nt++){
        int row = nt*16 + l15;
        vb[nt] = row*512 + ((l4 ^ (row&3))*16) + ((row&4)*16);
    }

#pragma unroll
    for(int nt=0; nt<NT; nt++){
        int n = base + nt*16 + l15;
        int b = n / (T_LEN*T_LEN);
        int r = n - b*(T_LEN*T_LEN);
        int q = r / T_LEN;
        int j = r - q*T_LEN;
        float ta = t[b*T_LEN + j], tb = t[b*T_LEN + q];
        t0v[nt] = ta; rat[nt] = tb - ta; rat2[nt] = bc2(tb - ta);
        const float* xr = x + (size_t)(b*T_LEN + j)*DM;
#pragma unroll
        for(int mt=0; mt<MT; mt++){
            const int db = 32*wvd + mt*16 + l4*4;
            f32x4 v = *(const f32x4*)(xr + db);
            y[mt][nt][0] = lo2(v); y[mt][nt][1] = hi2(v);
        }
    }

    auto put = [&](int idx, f32x2 v01, f32x2 v23){
        uint p0 = pkrtz(v01[0], v01[1]), p1 = pkrtz(v23[0], v23[1]);
        *(uint2*)&ylds[idx] = make_uint2(p0, p1);
    };

    // acc[mt][nt] = (W-slice) x Y^T over K=256; A from registers, B from LDS
    auto matmul = [&](const f16x8 (&Wf)[MT][8], int buf){
        const char* bb = (const char*)ylds + (buf<<14);
        __builtin_amdgcn_s_setprio(1);
#pragma unroll
        for(int mt=0; mt<MT; mt++)
#pragma unroll
            for(int nt=0; nt<NT; nt++)
                acc[mt][nt] = (f32x4){0.f,0.f,0.f,0.f};
#pragma unroll
        for(int ks=0; ks<8; ks++){
#pragma unroll
            for(int nt=0; nt<NT; nt++){
                f16x8 bh = *(const f16x8*)(bb + (vb[nt] ^ (ks<<6)));
#pragma unroll
                for(int mt=0; mt<MT; mt++)
                    acc[mt][nt] = __builtin_amdgcn_mfma_f32_16x16x32_f16(Wf[mt][ks], bh, acc[mt][nt], 0,0,0);
            }
        }
        __builtin_amdgcn_s_setprio(0);
    };

    // softplus + stage hidden into buf1 (after matmul1's acc)
    auto hidden = [&](const f32x2* tt2){
#pragma unroll
        for(int mt=0; mt<MT; mt++)
#pragma unroll
            for(int nt=0; nt<NT; nt++){
                f32x2 v[2];
#pragma unroll
                for(int p=0;p<2;p++){
                    f32x2 ap = p ? hi2(acc[mt][nt]) : lo2(acc[mt][nt]);
                    f32x2 s  = pk_fma(tt2[nt], U1h[mt][p], pk_add(ap, B1h[mt][p]));
                    v[p] = (f32x2){ softplus_f(s[0]), softplus_f(s[1]) };
                }
                put(BUF_USH + pofs[mt][nt], v[0], v[1]);
            }
    };

    // ---- initial stage of y into buf0
#pragma unroll
    for(int mt=0; mt<MT; mt++)
#pragma unroll
        for(int nt=0; nt<NT; nt++)
            put(pofs[mt][nt], y[mt][nt][0], y[mt][nt][1]);
    __syncthreads();

    const f32x2 neg1 = bc2(-1.f), four2 = bc2(4.f), three2 = bc2(3.f);

    float s0 = 0.f;
#pragma unroll 1
    for(int step=0; step<3; step++){
        const float s1 = (step==0) ? 0.1127016653792583f : ((step==1) ? 0.5f : 0.8872983346207417f);
        const float gw = ((step==1) ? 0.88888f : 0.55555f) * 0.5f;
        const float dt = s1 - s0;
        const float c3 = dt * (1.f/3.f);
        const f32x2 dt2 = bc2(dt), c32 = bc2(c3), nc32 = bc2(-c3), dt82 = bc2(dt*0.125f);
        const f32x2 gw2 = bc2(gw);
        f32x2 tt2[NT];

        // ---- E1
#pragma unroll
        for(int nt=0; nt<NT; nt++) tt2[nt] = bc2(t0v[nt] + s0*rat[nt]);
        matmul(W1f, 0);
        hidden(tt2);
        __syncthreads();
        matmul(W2f, 1);

        // ---- k1 extract; stage y + c3*k1 -> buf0
#pragma unroll
        for(int mt=0; mt<MT; mt++)
#pragma unroll
            for(int nt=0; nt<NT; nt++){
                f32x2 v[2];
#pragma unroll
                for(int p=0;p<2;p++){
                    f32x2 ap = p ? hi2(acc[mt][nt]) : lo2(acc[mt][nt]);
                    f32x2 kk = pk_mul(pk_fma(tt2[nt], U2h[mt][p], pk_add(ap, B2h[mt][p])), rat2[nt]);
                    k1[mt][nt][p] = kk;
                    v[p] = pk_fma(c32, kk, y[mt][nt][p]);
                }
                put(pofs[mt][nt], v[0], v[1]);
            }
        __syncthreads();

        // ---- E2
#pragma unroll
        for(int nt=0; nt<NT; nt++) tt2[nt] = bc2(t0v[nt] + (s0+c3)*rat[nt]);
        matmul(W1f, 0);
        hidden(tt2);
        __syncthreads();
        matmul(W2f, 1);

        // ---- k2 extract; stage y + dt*k2 - c3*k1 -> buf0; k1 <- d12 = k1-k2
#pragma unroll
        for(int mt=0; mt<MT; mt++)
#pragma unroll
            for(int nt=0; nt<NT; nt++){
                f32x2 v[2];
#pragma unroll
                for(int p=0;p<2;p++){
                    f32x2 ap = p ? hi2(acc[mt][nt]) : lo2(acc[mt][nt]);
                    f32x2 kk = pk_mul(pk_fma(tt2[nt], U2h[mt][p], pk_add(ap, B2h[mt][p])), rat2[nt]);
                    f32x2 k1o = k1[mt][nt][p];
                    v[p] = pk_fma(dt2, kk, pk_fma(nc32, k1o, y[mt][nt][p]));
                    k1[mt][nt][p] = pk_fma(kk, neg1, k1o);   // d12 = k1 - k2
                    k2[mt][nt][p] = kk;
                }
                put(pofs[mt][nt], v[0], v[1]);
            }
        __syncthreads();

        // ---- E3
#pragma unroll
        for(int nt=0; nt<NT; nt++) tt2[nt] = bc2(t0v[nt] + (s0+2.f*c3)*rat[nt]);
        matmul(W1f, 0);
        hidden(tt2);
        __syncthreads();
        matmul(W2f, 1);

        // ---- k3 extract: stage y + dt*(d12+k3) -> buf0;
        //      y += dt8*(d12 + 4*k2 + 3*k3)
#pragma unroll
        for(int mt=0; mt<MT; mt++)
#pragma unroll
            for(int nt=0; nt<NT; nt++){
                f32x2 v[2];
#pragma unroll
                for(int p=0;p<2;p++){
                    f32x2 ap = p ? hi2(acc[mt][nt]) : lo2(acc[mt][nt]);
                    f32x2 k3v = pk_mul(pk_fma(tt2[nt], U2h[mt][p], pk_add(ap, B2h[mt][p])), rat2[nt]);
                    f32x2 d12 = k1[mt][nt][p];
                    v[p] = pk_fma(dt2, pk_add(d12, k3v), y[mt][nt][p]);
                    f32x2 inner = pk_fma(four2, k2[mt][nt][p], pk_fma(three2, k3v, d12));
                    y[mt][nt][p] = pk_fma(dt82, inner, y[mt][nt][p]);
                }
                put(pofs[mt][nt], v[0], v[1]);
            }
        __syncthreads();

        // ---- E4
#pragma unroll
        for(int nt=0; nt<NT; nt++) tt2[nt] = bc2(t0v[nt] + s1*rat[nt]);
        matmul(W1f, 0);
        hidden(tt2);
        __syncthreads();
        matmul(W2f, 1);

        // ---- k4 fold + stage next y (buf0) + transpose scratch (yf, disjoint)
        {
            float* yf = (float*)&ylds[2*BUF_USH];   // [32 rows][256 f32], swizzled
#pragma unroll
            for(int mt=0; mt<MT; mt++)
#pragma unroll
                for(int nt=0; nt<NT; nt++){
                    const int row = nt*16 + l15;
                    f32x4 ov;
#pragma unroll
                    for(int p=0;p<2;p++){
                        f32x2 ap = p ? hi2(acc[mt][nt]) : lo2(acc[mt][nt]);
                        f32x2 k4v = pk_mul(pk_fma(tt2[nt], U2h[mt][p], pk_add(ap, B2h[mt][p])), rat2[nt]);
                        f32x2 yn  = pk_fma(dt82, k4v, y[mt][nt][p]);
                        y[mt][nt][p] = yn;
                        f32x2 o = pk_mul(yn, gw2);
                        ov[2*p] = o[0]; ov[2*p+1] = o[1];
                    }
                    put(pofs[mt][nt], y[mt][nt][0], y[mt][nt][1]);
                    const int c = 8*wvd + 4*mt + l4;
                    const int p2 = c ^ (row & 7);
                    *(f32x4*)&yf[row*256 + p2*4] = ov;
                }
            __syncthreads();
#pragma unroll
            for(int i=0;i<4;i++){
                const int r = 4*wvd + i;
                f32x4 v = *(const f32x4*)&yf[r*256 + ((lane ^ (r&7))&63)*4];
                __builtin_nontemporal_store(v,
                    (f32x4*)(out + ((size_t)(base + r)*3 + step)*DM + lane*4));
            }
        }
        s0 = s1;
    }
}

extern "C" void kernel_launch(void* const* d_in, const int* in_sizes, int n_in,
                              void* d_out, int out_size, void* d_ws, size_t ws_size,
                              hipStream_t stream)
{
    const float* x  = (const float*)d_in[0];
    const float* t  = (const float*)d_in[1];
    const float* W1 = (const float*)d_in[2];
    const float* b1 = (const float*)d_in[3];
    const float* u1 = (const float*)d_in[4];
    const float* W2 = (const float*)d_in[5];
    const float* b2 = (const float*)d_in[6];
    const float* u2 = (const float*)d_in[7];
    ushort* wpk = (ushort*)d_ws;     // 256 KB: W1f16 | W2f16 packed fragments

    pack_w_kernel<<<dim3(256,2), 256, 0, stream>>>(W1, W2, wpk);
    ode_mfma_kernel<<<dim3((4*T_LEN*T_LEN)/NSAMP), 512, 0, stream>>>(
        x, t, b1, u1, b2, u2, wpk, (float*)d_out);
}